// Round 11
// baseline (945.536 us; speedup 1.0000x reference)
//
#include <hip/hip_runtime.h>
#include <cstddef>

#define R_ 0.70710678118654752f
#define NEG_ 0.2f
#define EPS_ 1e-5f

constexpr int F_ = 64, C3_ = 192, HH_ = 128, NPIX_ = 16384, B_ = 4, LAT_ = 512, HYP_ = 33024;
// intra-row offsets inside one sample's hypernet output
constexpr int OFFI_WIN = 0, OFFI_BIN = 12288, OFFI_WMID = 12352, OFFI_BMID = 16448,
              OFFI_WOUT = 16512, OFFI_BOUT = 20608, OFFI_WSH = 20672, OFFI_BSH = 32960;
// workspace layout (float offsets)
constexpr size_t OFF_HYP = 0;         // 132096
constexpr size_t OFF_SRAW = 134144;   // 6144
constexpr size_t OFF_WFIN = 140288;   // 4*24576 ushort = 49152 floats (hi/lo frag pairs)
constexpr size_t OFF_WFSH = 189440;   // 49152
constexpr size_t OFF_WFMID = 238592;  // 4*8192 ushort = 16384 floats
constexpr size_t OFF_WFOUT = 254976;  // 16384
constexpr size_t OFF_CW1 = 271360;    // 73728 ushort = 36864 floats (split-bf16 frag pairs)
constexpr size_t OFF_CW2 = 308224;    // 36864
constexpr size_t OFF_CWIMG = 345088;  // 1728
constexpr size_t OFF_OUT = 346816;    // 4194304
constexpr size_t OFF_SOB = 4541120;   // 4*128*16384 packed-uint = 8388608 "floats"
constexpr size_t OFF_TMP = OFF_SOB;   // epilogue h (fp32, 4194304) aliases sob
// total = 12,929,728 floats = 51.7 MB

typedef short bf16x8 __attribute__((ext_vector_type(8)));
typedef float f32x4 __attribute__((ext_vector_type(4)));

// fp32 -> bf16 (RNE)
static __device__ __forceinline__ unsigned short f2b(float v) {
  unsigned u = __builtin_bit_cast(unsigned, v);
  u += 0x7fffu + ((u >> 16) & 1u);
  return (unsigned short)(u >> 16);
}
static __device__ __forceinline__ float b2f(unsigned short h) {
  return __builtin_bit_cast(float, ((unsigned)h) << 16);
}
static __device__ __forceinline__ void split2(float v, unsigned short& hi, unsigned short& lo) {
  hi = f2b(v);
  lo = f2b(v - b2f(hi));
}

// triple-MFMA split-bf16 product: acc += Ahi*Whi + Ahi*Wlo + Alo*Whi
#define MM3(acc, ahi, alo, whi, wlo)                                        \
  acc = __builtin_amdgcn_mfma_f32_16x16x32_bf16(ahi, whi, acc, 0, 0, 0);    \
  acc = __builtin_amdgcn_mfma_f32_16x16x32_bf16(ahi, wlo, acc, 0, 0, 0);    \
  acc = __builtin_amdgcn_mfma_f32_16x16x32_bf16(alo, whi, acc, 0, 0, 0);

// ---------------- hypernetwork GEMM ----------------------------------------------
__global__ __launch_bounds__(256) void hyper_gemm_kernel(
    const float* __restrict__ lat, const float* __restrict__ hw,
    const float* __restrict__ hb, float* __restrict__ hyp) {
  __shared__ float slat[B_ * LAT_];
  const int tid = threadIdx.x;
  for (int i = tid; i < B_ * LAT_; i += 256) slat[i] = lat[i];
  __syncthreads();
  const int wave = tid >> 6, lane = tid & 63;
  const int j = blockIdx.x * 4 + wave;
  if (j >= HYP_) return;
  const float* wr = hw + (size_t)j * LAT_;
  float a0 = 0.f, a1 = 0.f, a2 = 0.f, a3 = 0.f;
  for (int i = 0; i < LAT_; i += 64) {
    float w = wr[i + lane];
    a0 = __builtin_fmaf(w, slat[0 * LAT_ + i + lane], a0);
    a1 = __builtin_fmaf(w, slat[1 * LAT_ + i + lane], a1);
    a2 = __builtin_fmaf(w, slat[2 * LAT_ + i + lane], a2);
    a3 = __builtin_fmaf(w, slat[3 * LAT_ + i + lane], a3);
  }
  #pragma unroll
  for (int off = 32; off; off >>= 1) {
    a0 += __shfl_down(a0, off, 64);
    a1 += __shfl_down(a1, off, 64);
    a2 += __shfl_down(a2, off, 64);
    a3 += __shfl_down(a3, off, 64);
  }
  if (lane == 0) {
    float b = hb[j];
    hyp[0 * HYP_ + j] = a0 + b;
    hyp[1 * HYP_ + j] = a1 + b;
    hyp[2 * HYP_ + j] = a2 + b;
    hyp[3 * HYP_ + j] = a3 + b;
  }
}

// ---------------- dynamic weights -> STATIC split-bf16 frag layout (once) ---------
__global__ __launch_bounds__(256) void prep_dynw_kernel(float* wsm) {
  const int b = blockIdx.x >> 3, sl = blockIdx.x & 7;
  const int tid = threadIdx.x;
  const float* hyp = wsm + OFF_HYP + (size_t)b * HYP_;
  unsigned short* wfin = (unsigned short*)(wsm + OFF_WFIN) + (size_t)b * 24576;
  unsigned short* wfsh = (unsigned short*)(wsm + OFF_WFSH) + (size_t)b * 24576;
  unsigned short* wfmid = (unsigned short*)(wsm + OFF_WFMID) + (size_t)b * 8192;
  unsigned short* wfout = (unsigned short*)(wsm + OFF_WFOUT) + (size_t)b * 8192;

  if (sl < 6) {
    const int base = sl * 2048;
    for (int i = tid; i < 2048; i += 256) {
      int idx = base + i;
      int j = idx & 7, ch = (idx >> 3) & 63, g2 = (idx >> 9) & 3, ks = idx >> 11;
      int k = ks * 32 + g2 * 8 + j;
      int fbx = ((ks * 4 + g2) * 64 + ch) * 16;
      unsigned short h, l;
      split2(hyp[OFFI_WIN + ch * C3_ + k], h, l);
      wfin[fbx + j] = h; wfin[fbx + 8 + j] = l;
      split2(hyp[OFFI_WSH + ch * C3_ + k], h, l);
      wfsh[fbx + j] = h; wfsh[fbx + 8 + j] = l;
    }
  } else if (sl == 6) {
    for (int idx = tid; idx < 4096; idx += 256) {
      int j = idx & 7, ch = (idx >> 3) & 63, g2 = (idx >> 9) & 3, ks = idx >> 11;
      int k = ks * 32 + g2 * 8 + j;
      int fbx = ((ks * 4 + g2) * 64 + ch) * 16;
      unsigned short h, l;
      split2(hyp[OFFI_WMID + ch * 64 + k], h, l);
      wfmid[fbx + j] = h; wfmid[fbx + 8 + j] = l;
      split2(hyp[OFFI_WOUT + ch * 64 + k], h, l);
      wfout[fbx + j] = h; wfout[fbx + 8 + j] = l;
    }
  }
}

// ---------------- conv weights -> split-bf16 frag layout (+ img transpose) --------
__global__ __launch_bounds__(256) void prep_convw_kernel(
    const float* __restrict__ w1, const float* __restrict__ w2,
    const float* __restrict__ wi, unsigned short* __restrict__ wf1,
    unsigned short* __restrict__ wf2, float* __restrict__ wit) {
  const int idx = blockIdx.x * 256 + threadIdx.x;
  if (idx < 36864) {
    int j = idx & 7, ch = (idx >> 3) & 63, fg = idx >> 9;  // fg = ks*4+g
    int k = (fg >> 2) * 32 + (fg & 3) * 8 + j;
    int c = k & 63, t = k >> 6;
    int fb = (fg * 64 + ch) * 16;
    unsigned short h, l;
    split2(w1[(ch * 64 + c) * 9 + t], h, l);
    wf1[fb + j] = h; wf1[fb + 8 + j] = l;
    split2(w2[(ch * 64 + c) * 9 + t], h, l);
    wf2[fb + j] = h; wf2[fb + 8 + j] = l;
  }
  if (idx < 64 * 9 * 3) {
    int k = idx % 3, rest = idx / 3;
    int t = rest % 9, c = rest / 9;
    wit[idx] = wi[(k * 64 + c) * 9 + t];
  }
}

// ---------------- block reduction helper ------------------------------------------
__device__ __forceinline__ float blockReduceSum(float v, float* scratch) {
  const int tid = threadIdx.x;
  #pragma unroll
  for (int off = 32; off; off >>= 1) v += __shfl_down(v, off, 64);
  if ((tid & 63) == 0) scratch[tid >> 6] = v;
  __syncthreads();
  float r = scratch[0] + scratch[1] + scratch[2] + scratch[3];
  __syncthreads();
  return r;
}

__device__ __forceinline__ void hline_z(const float* __restrict__ P, int rr, int col,
                                        float& hdv, float& hsv, float& cv) {
  if (rr < 0 || rr > 127) { hdv = 0.f; hsv = 0.f; cv = 0.f; return; }
  const float* rp = P + rr * HH_;
  float vm2 = (col >= 2) ? rp[col - 2] : 0.f;
  float vm1 = (col >= 1) ? rp[col - 1] : 0.f;
  float v0 = rp[col];
  float vp1 = (col <= 126) ? rp[col + 1] : 0.f;
  float vp2 = (col <= 125) ? rp[col + 2] : 0.f;
  hdv = -vm2 - R_ * vm1 + R_ * vp1 + vp2;
  hsv = R_ * vm1 + v0 + R_ * vp1;
  cv = v0;
}

// ---------------- SinSobel -> packed split-bf16 gx/gy + raw IN partials -----------
__global__ __launch_bounds__(256) void sobel_stats_kernel(
    const float* __restrict__ outb, unsigned int* __restrict__ sob,
    float* __restrict__ sraw) {
  __shared__ float scr[4];
  const int bi = blockIdx.x;
  const int q = bi & 3, c = (bi >> 2) & 63, b = bi >> 8;
  const int tid = threadIdx.x;
  const int col = tid & 127;
  const int r0 = q * 32 + (tid >> 7) * 16;
  const float* P = outb + ((size_t)(b * F_ + c)) * NPIX_;
  unsigned int* ygx = sob + ((size_t)(b * 128 + 2 * c)) * NPIX_;
  unsigned int* ygy = ygx + NPIX_;

  float sI = 0.f, qI = 0.f, sX = 0.f, qX = 0.f, sY = 0.f, qY = 0.f;
  float hd_m1, hd_0, hd_p1, hs_m2, hs_m1, hs_0, hs_p1;
  float td, tc;
  hline_z(P, r0 - 2, col, td, hs_m2, tc);
  hline_z(P, r0 - 1, col, hd_m1, hs_m1, tc);
  hline_z(P, r0, col, hd_0, hs_0, tc);
  sI += tc; qI += tc * tc;
  hline_z(P, r0 + 1, col, hd_p1, hs_p1, tc);
  sI += tc; qI += tc * tc;

  for (int i = 0; i < 16; ++i) {
    const int r = r0 + i;
    const int nr = r + 2;
    float hd_new, hs_new, cnew;
    hline_z(P, nr, col, hd_new, hs_new, cnew);
    if (nr <= r0 + 15) { sI += cnew; qI += cnew * cnew; }
    float gxv = R_ * (hd_m1 + hd_p1) + hd_0;
    float gyv = -hs_m2 - R_ * hs_m1 + R_ * hs_p1 + hs_new;
    const int o = r * HH_ + col;
    unsigned short h, l;
    split2(gxv, h, l);
    ygx[o] = ((unsigned)h << 16) | l;
    split2(gyv, h, l);
    ygy[o] = ((unsigned)h << 16) | l;
    sX += gxv; qX += gxv * gxv;
    sY += gyv; qY += gyv * gyv;
    hd_m1 = hd_0; hd_0 = hd_p1; hd_p1 = hd_new;
    hs_m2 = hs_m1; hs_m1 = hs_0; hs_0 = hs_p1; hs_p1 = hs_new;
  }
  __syncthreads();
  float tI = blockReduceSum(sI, scr);
  float tQI = blockReduceSum(qI, scr);
  float tX = blockReduceSum(sX, scr);
  float tQX = blockReduceSum(qX, scr);
  float tY = blockReduceSum(sY, scr);
  float tQY = blockReduceSum(qY, scr);
  if (tid == 0) {
    float* r = sraw + (size_t)bi * 6;
    r[0] = tI; r[1] = tQI; r[2] = tX; r[3] = tQX; r[4] = tY; r[5] = tQY;
  }
}

// ---------------- MFMA dynamic MLP, split-bf16, wave-per-cg-slice -----------------
// T14 async-STAGE: all 12 staging loads issued into registers BEFORE the stats
// phase; unpack/split after the barrier. res-trick: C reconstructed in LDS.
__global__ __launch_bounds__(256, 2) void mlp_mfma_kernel(
    float* __restrict__ outb, const unsigned int* __restrict__ sobu,
    const float* __restrict__ wsf, const float* __restrict__ leak) {
  __shared__ unsigned short yhi[64 * 200];
  __shared__ unsigned short ylo[64 * 200];
  __shared__ unsigned short hhi[64 * 72];
  __shared__ unsigned short hlo[64 * 72];
  __shared__ unsigned short resb[64 * 66];
  __shared__ float stl[C3_ * 2];
  __shared__ float ssig[64];
  const int bi = blockIdx.x;
  const int b = bi >> 8, t = bi & 255;
  const int px0 = t * 64;
  const int tid = threadIdx.x;

  // ---- issue ALL staging loads first (latency hides under stats finalize) ----
  const float* ob = outb + (size_t)b * F_ * NPIX_;
  const unsigned int* sbp = sobu + (size_t)b * 128 * NPIX_;
  uint4 vbuf[12];
  #pragma unroll
  for (int it = 0; it < 12; ++it) {
    const int ci = it * 256 + tid;
    const int k = ci >> 4, pq = ci & 15;
    const unsigned int* src =
        (k < 64) ? (const unsigned int*)(ob + (size_t)k * NPIX_ + px0 + pq * 4)
                 : (sbp + (size_t)(k - 64) * NPIX_ + px0 + pq * 4);
    vbuf[it] = *(const uint4*)src;
  }

  // finalize InstanceNorm stats for this sample (64 threads x 3 channels each)
  if (tid < 64) {
    const int c = tid;
    const float* r = wsf + OFF_SRAW + ((size_t)(b * 64 + c) * 4) * 6;
    float sI = 0.f, qI = 0.f, sX = 0.f, qX = 0.f, sY = 0.f, qY = 0.f;
    #pragma unroll
    for (int q = 0; q < 4; ++q) {
      sI += r[q * 6 + 0]; qI += r[q * 6 + 1];
      sX += r[q * 6 + 2]; qX += r[q * 6 + 3];
      sY += r[q * 6 + 4]; qY += r[q * 6 + 5];
    }
    const float n = 1.f / 16384.f;
    float m, rs;
    m = sI * n; rs = rsqrtf(qI * n - m * m + EPS_);
    stl[c * 2] = m; stl[c * 2 + 1] = rs; ssig[c] = 1.f / rs;
    const int cx = 64 + 2 * c, cy = cx + 1;
    m = sX * n; stl[cx * 2] = m;          stl[cx * 2 + 1] = rsqrtf(qX * n - m * m + EPS_);
    m = sY * n; stl[cy * 2] = m;          stl[cy * 2 + 1] = rsqrtf(qY * n - m * m + EPS_);
  }
  __syncthreads();

  // ---- unpack + normalize + split into LDS ----
  #pragma unroll
  for (int it = 0; it < 12; ++it) {
    const int ci = it * 256 + tid;
    const int k = ci >> 4, pq = ci & 15;
    const int kk = k ^ ((pq >> 1) << 3);
    unsigned short* ph = &yhi[(pq * 4) * 200 + kk];
    unsigned short* pl = &ylo[(pq * 4) * 200 + kk];
    const float mu = stl[k * 2], inv = stl[k * 2 + 1];
    const uint4 v = vbuf[it];
    if (k < 64) {
      const float sg = ssig[k];
      const float vv[4] = {__builtin_bit_cast(float, v.x), __builtin_bit_cast(float, v.y),
                           __builtin_bit_cast(float, v.z), __builtin_bit_cast(float, v.w)};
      #pragma unroll
      for (int e = 0; e < 4; ++e) {
        unsigned short h, l;
        split2((vv[e] - mu) * inv, h, l);
        ph[e * 200] = h; pl[e * 200] = l;
        float rec = __builtin_fmaf(b2f(h) + b2f(l), sg, mu);
        resb[k * 66 + pq * 4 + e] = f2b(vv[e] - rec);
      }
    } else {
      const unsigned uu[4] = {v.x, v.y, v.z, v.w};
      #pragma unroll
      for (int e = 0; e < 4; ++e) {
        float val = b2f((unsigned short)(uu[e] >> 16)) + b2f((unsigned short)(uu[e] & 0xffff));
        unsigned short h, l;
        split2((val - mu) * inv, h, l);
        ph[e * 200] = h; pl[e * 200] = l;
      }
    }
  }
  __syncthreads();

  const int wave = tid >> 6, lane = tid & 63;
  const int lrow = lane & 15, g = lane >> 4;
  const int chm = wave * 16 + lrow;  // this wave's output-channel for this lane
  const float lf = fminf(fmaxf(leak[0], 0.001f), 1000.f);
  const float* hyp = wsf + OFF_HYP + (size_t)b * HYP_;
  const unsigned short* wfin = (const unsigned short*)(wsf + OFF_WFIN) + (size_t)b * 24576;
  const unsigned short* wfsh = (const unsigned short*)(wsf + OFF_WFSH) + (size_t)b * 24576;
  const unsigned short* wfmid = (const unsigned short*)(wsf + OFF_WFMID) + (size_t)b * 8192;
  const unsigned short* wfout = (const unsigned short*)(wsf + OFF_WFOUT) + (size_t)b * 8192;

  // ---- phase 1: h1 + shortcut (K = 192), B-frag shared across 4 px-frags ----
  f32x4 aH[4], aS[4];
  {
    float b1 = hyp[OFFI_BIN + chm], b2 = hyp[OFFI_BSH + chm];
    #pragma unroll
    for (int pf = 0; pf < 4; ++pf) {
      aH[pf] = (f32x4){b1, b1, b1, b1};
      aS[pf] = (f32x4){b2, b2, b2, b2};
    }
  }
  #pragma unroll
  for (int ks = 0; ks < 6; ++ks) {
    const size_t wo = (size_t)((ks * 4 + g) * 64 + chm) * 16;
    bf16x8 whiI = *(const bf16x8*)(wfin + wo);
    bf16x8 wloI = *(const bf16x8*)(wfin + wo + 8);
    bf16x8 whiS = *(const bf16x8*)(wfsh + wo);
    bf16x8 wloS = *(const bf16x8*)(wfsh + wo + 8);
    #pragma unroll
    for (int pf = 0; pf < 4; ++pf) {
      const int pxl = pf * 16 + lrow;
      const int kb = pxl * 200 + ((ks * 32 + g * 8) ^ ((pxl >> 3) << 3));
      bf16x8 ahi = *(const bf16x8*)&yhi[kb];
      bf16x8 alo = *(const bf16x8*)&ylo[kb];
      MM3(aH[pf], ahi, alo, whiI, wloI);
      MM3(aS[pf], ahi, alo, whiS, wloS);
    }
  }
  // lrelu(h1) -> htile: px = pf*16 + g*4 + j, ch = chm
  #pragma unroll
  for (int pf = 0; pf < 4; ++pf) {
    #pragma unroll
    for (int j = 0; j < 4; ++j) {
      float v = aH[pf][j];
      v = (v >= 0.f) ? v : NEG_ * v;
      unsigned short h, l;
      split2(v, h, l);
      const int o = (pf * 16 + g * 4 + j) * 72 + chm;
      hhi[o] = h; hlo[o] = l;
    }
  }
  __syncthreads();
  // ---- phase 2: h2 (K = 64) ----
  f32x4 aM[4];
  {
    float bm = hyp[OFFI_BMID + chm];
    #pragma unroll
    for (int pf = 0; pf < 4; ++pf) aM[pf] = (f32x4){bm, bm, bm, bm};
  }
  #pragma unroll
  for (int ks = 0; ks < 2; ++ks) {
    const size_t wo = (size_t)((ks * 4 + g) * 64 + chm) * 16;
    bf16x8 whi = *(const bf16x8*)(wfmid + wo);
    bf16x8 wlo = *(const bf16x8*)(wfmid + wo + 8);
    #pragma unroll
    for (int pf = 0; pf < 4; ++pf) {
      const int kb = (pf * 16 + lrow) * 72 + ks * 32 + g * 8;
      bf16x8 ahi = *(const bf16x8*)&hhi[kb];
      bf16x8 alo = *(const bf16x8*)&hlo[kb];
      MM3(aM[pf], ahi, alo, whi, wlo);
    }
  }
  __syncthreads();
  #pragma unroll
  for (int pf = 0; pf < 4; ++pf) {
    #pragma unroll
    for (int j = 0; j < 4; ++j) {
      float v = aM[pf][j];
      v = (v >= 0.f) ? v : NEG_ * v;
      unsigned short h, l;
      split2(v, h, l);
      const int o = (pf * 16 + g * 4 + j) * 72 + chm;
      hhi[o] = h; hlo[o] = l;
    }
  }
  __syncthreads();
  // ---- phase 3: h3 (K = 64) ----
  f32x4 aO[4];
  {
    float bo = hyp[OFFI_BOUT + chm];
    #pragma unroll
    for (int pf = 0; pf < 4; ++pf) aO[pf] = (f32x4){bo, bo, bo, bo};
  }
  #pragma unroll
  for (int ks = 0; ks < 2; ++ks) {
    const size_t wo = (size_t)((ks * 4 + g) * 64 + chm) * 16;
    bf16x8 whi = *(const bf16x8*)(wfout + wo);
    bf16x8 wlo = *(const bf16x8*)(wfout + wo + 8);
    #pragma unroll
    for (int pf = 0; pf < 4; ++pf) {
      const int kb = (pf * 16 + lrow) * 72 + ks * 32 + g * 8;
      bf16x8 ahi = *(const bf16x8*)&hhi[kb];
      bf16x8 alo = *(const bf16x8*)&hlo[kb];
      MM3(aO[pf], ahi, alo, whi, wlo);
    }
  }
  // ---- out = recon(ynorm, res) + lf*(h3 + shortcut): WRITE-ONLY to global ----
  const float mu_c = stl[chm * 2];
  const float sg_c = ssig[chm];
  #pragma unroll
  for (int pf = 0; pf < 4; ++pf) {
    float* op = outb + ((size_t)(b * F_ + chm)) * NPIX_ + px0 + pf * 16 + g * 4;
    f32x4 nv;
    #pragma unroll
    for (int j = 0; j < 4; ++j) {
      const int pxl = pf * 16 + g * 4 + j;
      const int kk2 = chm ^ ((pxl >> 3) << 3);
      float yv = b2f(yhi[pxl * 200 + kk2]) + b2f(ylo[pxl * 200 + kk2]);
      float vorig = __builtin_fmaf(yv, sg_c, mu_c) + b2f(resb[chm * 66 + pxl]);
      nv[j] = vorig + lf * (aO[pf][j] + aS[pf][j]);
    }
    *(f32x4*)op = nv;
  }
}

// ---------------- MFMA 3x3 conv (implicit GEMM, split-bf16, 2-row tiles) ----------
// block = (b, row-pair, col-half): stages 4 halo rows x 72 cols (overfetch 2.25x
// vs 3.4x for 1-row tiles), computes 2 rows x 64 cols. Weight frags loaded once
// per ks, reused for both rows. grid = 512.
__global__ __launch_bounds__(256, 2) void conv_mfma_kernel(
    const float* __restrict__ in, const unsigned short* __restrict__ wf,
    const float* __restrict__ bias, float* __restrict__ dst, int mode) {
  __shared__ unsigned short ahi[4 * 72 * 64];
  __shared__ unsigned short alo[4 * 72 * 64];
  const int bi = blockIdx.x;
  const int b = bi >> 7, rest = bi & 127;
  const int row0 = (rest >> 1) * 2, colbase = (rest & 1) << 6;
  const int tid = threadIdx.x;
  const float* ip = in + (size_t)b * F_ * NPIX_;

  for (int idx = tid; idx < 4608; idx += 256) {
    const int chunk = idx % 18;
    const int rowp = (idx / 18) % 4;
    const int ch = idx / 72;
    const int r2 = row0 - 1 + rowp;
    const int gcol0 = colbase - 4 + chunk * 4;
    float4 v;
    if (r2 < 0 || r2 > 127) {
      v = make_float4(0.f, 0.f, 0.f, 0.f);
    } else if (gcol0 >= 0 && gcol0 <= 124) {
      v = *(const float4*)(ip + (size_t)ch * NPIX_ + r2 * HH_ + gcol0);
    } else {
      const float* rp = ip + (size_t)ch * NPIX_ + r2 * HH_;
      v.x = (gcol0 >= 0 && gcol0 < 128) ? rp[gcol0] : 0.f;
      v.y = (gcol0 + 1 >= 0 && gcol0 + 1 < 128) ? rp[gcol0 + 1] : 0.f;
      v.z = (gcol0 + 2 >= 0 && gcol0 + 2 < 128) ? rp[gcol0 + 2] : 0.f;
      v.w = (gcol0 + 3 >= 0 && gcol0 + 3 < 128) ? rp[gcol0 + 3] : 0.f;
    }
    const float vv[4] = {v.x, v.y, v.z, v.w};
    #pragma unroll
    for (int e = 0; e < 4; ++e) {
      const int i = chunk * 4 + e;
      const int sw = (((i >> 2) & 7) ^ ((i & 3) << 1) ^ rowp) << 3;
      const int a = (rowp * 72 + i) * 64 + (ch ^ sw);
      unsigned short h, l;
      split2(vv[e], h, l);
      ahi[a] = h; alo[a] = l;
    }
  }
  __syncthreads();

  const int wave = tid >> 6, lane = tid & 63;
  const int lrow = lane & 15, g = lane >> 4;
  const int pxl = wave * 16 + lrow;
  f32x4 acc0[4], acc1[4];
  #pragma unroll
  for (int cg = 0; cg < 4; ++cg) {
    float bz = bias[cg * 16 + lrow];
    acc0[cg] = (f32x4){bz, bz, bz, bz};
    acc1[cg] = (f32x4){bz, bz, bz, bz};
  }
  for (int ks = 0; ks < 18; ++ks) {
    const int kbase = ks * 32 + g * 8;
    const int t = kbase >> 6, c0 = kbase & 63;
    const int dy = t / 3 - 1, dx = t % 3 - 1;
    const int i = pxl + 4 + dx;
    const int rp0 = 1 + dy, rp1 = 2 + dy;
    const int sw0 = (((i >> 2) & 7) ^ ((i & 3) << 1) ^ rp0) << 3;
    const int sw1 = (((i >> 2) & 7) ^ ((i & 3) << 1) ^ rp1) << 3;
    const int a0 = (rp0 * 72 + i) * 64 + (c0 ^ sw0);
    const int a1 = (rp1 * 72 + i) * 64 + (c0 ^ sw1);
    bf16x8 ah0 = *(const bf16x8*)&ahi[a0];
    bf16x8 al0 = *(const bf16x8*)&alo[a0];
    bf16x8 ah1 = *(const bf16x8*)&ahi[a1];
    bf16x8 al1 = *(const bf16x8*)&alo[a1];
    #pragma unroll
    for (int cg = 0; cg < 4; ++cg) {
      const unsigned short* wp = wf + (size_t)((ks * 4 + g) * 64 + cg * 16 + lrow) * 16;
      bf16x8 whi = *(const bf16x8*)wp;
      bf16x8 wlo = *(const bf16x8*)(wp + 8);
      MM3(acc0[cg], ah0, al0, whi, wlo);
      MM3(acc1[cg], ah1, al1, whi, wlo);
    }
  }
  #pragma unroll
  for (int r = 0; r < 2; ++r) {
    #pragma unroll
    for (int cg = 0; cg < 4; ++cg) {
      const f32x4 av = r ? acc1[cg] : acc0[cg];
      float* op = dst + ((size_t)(b * F_ + cg * 16 + lrow)) * NPIX_ + (row0 + r) * HH_ +
                  colbase + wave * 16 + g * 4;
      if (mode == 1) {
        f32x4 rr;
        #pragma unroll
        for (int j = 0; j < 4; ++j) {
          float v = av[j];
          rr[j] = (v >= 0.f) ? v : NEG_ * v;
        }
        *(f32x4*)op = rr;
      } else {
        f32x4 cur = *(f32x4*)op;
        #pragma unroll
        for (int j = 0; j < 4; ++j) cur[j] += av[j];
        *(f32x4*)op = cur;
      }
    }
  }
}

// ---------------- final image conv (3 outputs, VALU) ------------------------------
__global__ __launch_bounds__(256, 4) void convimg_kernel(
    const float* __restrict__ outb, const float* __restrict__ wT,
    const float* __restrict__ bias, float* __restrict__ img) {
  __shared__ float part[2 * 128 * 3];
  const int bi = blockIdx.x;
  const int b = bi >> 7, pxb = bi & 127;
  const int tid = threadIdx.x;
  const int px = tid & 127;
  const int hf = __builtin_amdgcn_readfirstlane(tid >> 7);
  const int p = pxb * 128 + px;
  const int row = p >> 7, col = p & 127;
  float a0 = 0.f, a1 = 0.f, a2 = 0.f;
  const float* ip = outb + (size_t)b * F_ * NPIX_;
  for (int cc = 0; cc < 32; ++cc) {
    const int c = hf * 32 + cc;
    const float* pl = ip + (size_t)c * NPIX_;
    #pragma unroll
    for (int t = 0; t < 9; ++t) {
      const int dy = t / 3 - 1, dx = t % 3 - 1;
      const int r2 = row + dy, c2 = col + dx;
      float v = (r2 >= 0 && r2 < 128 && c2 >= 0 && c2 < 128) ? pl[r2 * HH_ + c2] : 0.f;
      const float* wp = wT + (c * 9 + t) * 3;
      a0 = __builtin_fmaf(v, wp[0], a0);
      a1 = __builtin_fmaf(v, wp[1], a1);
      a2 = __builtin_fmaf(v, wp[2], a2);
    }
  }
  part[(hf * 128 + px) * 3 + 0] = a0;
  part[(hf * 128 + px) * 3 + 1] = a1;
  part[(hf * 128 + px) * 3 + 2] = a2;
  __syncthreads();
  if (hf == 0) {
    float r0 = a0 + part[(128 + px) * 3 + 0] + bias[0];
    float r1 = a1 + part[(128 + px) * 3 + 1] + bias[1];
    float r2 = a2 + part[(128 + px) * 3 + 2] + bias[2];
    img[((size_t)b * 3 + 0) * NPIX_ + p] = fminf(fmaxf(r0, -1.f), 1.f);
    img[((size_t)b * 3 + 1) * NPIX_ + p] = fminf(fmaxf(r1, -1.f), 1.f);
    img[((size_t)b * 3 + 2) * NPIX_ + p] = fminf(fmaxf(r2, -1.f), 1.f);
  }
}

extern "C" void kernel_launch(void* const* d_in, const int* in_sizes, int n_in,
                              void* d_out, int out_size, void* d_ws, size_t ws_size,
                              hipStream_t stream) {
  const float* lat = (const float*)d_in[0];
  const float* ca_init = (const float*)d_in[1];
  const float* leak = (const float*)d_in[2];
  const float* hyper_w = (const float*)d_in[3];
  const float* hyper_b = (const float*)d_in[4];
  const float* res_w1 = (const float*)d_in[5];
  const float* res_b1 = (const float*)d_in[6];
  const float* res_w2 = (const float*)d_in[7];
  const float* res_b2 = (const float*)d_in[8];
  const float* img_w = (const float*)d_in[9];
  const float* img_b = (const float*)d_in[10];
  float* out = (float*)d_out;
  float* ws = (float*)d_ws;
  unsigned int* sobu = (unsigned int*)(ws + OFF_SOB);

  hyper_gemm_kernel<<<(HYP_ + 3) / 4, 256, 0, stream>>>(lat, hyper_w, hyper_b, ws + OFF_HYP);
  prep_dynw_kernel<<<32, 256, 0, stream>>>(ws);
  prep_convw_kernel<<<144, 256, 0, stream>>>(res_w1, res_w2, img_w,
                                             (unsigned short*)(ws + OFF_CW1),
                                             (unsigned short*)(ws + OFF_CW2),
                                             ws + OFF_CWIMG);
  hipMemcpyAsync(ws + OFF_OUT, ca_init, (size_t)B_ * F_ * NPIX_ * sizeof(float),
                 hipMemcpyDeviceToDevice, stream);

  for (int st = 0; st < 16; ++st) {
    sobel_stats_kernel<<<1024, 256, 0, stream>>>(ws + OFF_OUT, sobu, ws + OFF_SRAW);
    mlp_mfma_kernel<<<1024, 256, 0, stream>>>(ws + OFF_OUT, sobu, ws, leak);
  }

  conv_mfma_kernel<<<512, 256, 0, stream>>>(ws + OFF_OUT, (const unsigned short*)(ws + OFF_CW1),
                                            res_b1, (float*)(ws + OFF_TMP), 1);
  conv_mfma_kernel<<<512, 256, 0, stream>>>((const float*)(ws + OFF_TMP),
                                            (const unsigned short*)(ws + OFF_CW2),
                                            res_b2, ws + OFF_OUT, 2);
  convimg_kernel<<<512, 256, 0, stream>>>(ws + OFF_OUT, ws + OFF_CWIMG, img_b, out);
}

// Round 12
// 879.784 us; speedup vs baseline: 1.0747x; 1.0747x over previous
//
#include <hip/hip_runtime.h>
#include <cstddef>

#define R_ 0.70710678118654752f
#define NEG_ 0.2f
#define EPS_ 1e-5f

constexpr int F_ = 64, C3_ = 192, HH_ = 128, NPIX_ = 16384, B_ = 4, LAT_ = 512, HYP_ = 33024;
// intra-row offsets inside one sample's hypernet output
constexpr int OFFI_WIN = 0, OFFI_BIN = 12288, OFFI_WMID = 12352, OFFI_BMID = 16448,
              OFFI_WOUT = 16512, OFFI_BOUT = 20608, OFFI_WSH = 20672, OFFI_BSH = 32960;
// workspace layout (float offsets)
constexpr size_t OFF_HYP = 0;         // 132096
constexpr size_t OFF_SRAW = 134144;   // 6144
constexpr size_t OFF_WFIN = 140288;   // 4*24576 ushort = 49152 floats (hi/lo frag pairs)
constexpr size_t OFF_WFSH = 189440;   // 49152
constexpr size_t OFF_WFMID = 238592;  // 4*8192 ushort = 16384 floats
constexpr size_t OFF_WFOUT = 254976;  // 16384
constexpr size_t OFF_CW1 = 271360;    // 73728 ushort = 36864 floats (split-bf16 frag pairs)
constexpr size_t OFF_CW2 = 308224;    // 36864
constexpr size_t OFF_CWIMG = 345088;  // 1728
constexpr size_t OFF_OUT = 346816;    // 4194304
constexpr size_t OFF_SOB = 4541120;   // 4*128*16384 packed-uint = 8388608 "floats"
constexpr size_t OFF_TMP = OFF_SOB;   // epilogue h (fp32, 4194304) aliases sob
// total = 12,929,728 floats = 51.7 MB

typedef short bf16x8 __attribute__((ext_vector_type(8)));
typedef float f32x4 __attribute__((ext_vector_type(4)));

// fp32 -> bf16 (RNE)
static __device__ __forceinline__ unsigned short f2b(float v) {
  unsigned u = __builtin_bit_cast(unsigned, v);
  u += 0x7fffu + ((u >> 16) & 1u);
  return (unsigned short)(u >> 16);
}
static __device__ __forceinline__ float b2f(unsigned short h) {
  return __builtin_bit_cast(float, ((unsigned)h) << 16);
}
static __device__ __forceinline__ void split2(float v, unsigned short& hi, unsigned short& lo) {
  hi = f2b(v);
  lo = f2b(v - b2f(hi));
}

// triple-MFMA split-bf16 product: acc += Ahi*Whi + Ahi*Wlo + Alo*Whi
#define MM3(acc, ahi, alo, whi, wlo)                                        \
  acc = __builtin_amdgcn_mfma_f32_16x16x32_bf16(ahi, whi, acc, 0, 0, 0);    \
  acc = __builtin_amdgcn_mfma_f32_16x16x32_bf16(ahi, wlo, acc, 0, 0, 0);    \
  acc = __builtin_amdgcn_mfma_f32_16x16x32_bf16(alo, whi, acc, 0, 0, 0);

// ---------------- hypernetwork GEMM ----------------------------------------------
__global__ __launch_bounds__(256) void hyper_gemm_kernel(
    const float* __restrict__ lat, const float* __restrict__ hw,
    const float* __restrict__ hb, float* __restrict__ hyp) {
  __shared__ float slat[B_ * LAT_];
  const int tid = threadIdx.x;
  for (int i = tid; i < B_ * LAT_; i += 256) slat[i] = lat[i];
  __syncthreads();
  const int wave = tid >> 6, lane = tid & 63;
  const int j = blockIdx.x * 4 + wave;
  if (j >= HYP_) return;
  const float* wr = hw + (size_t)j * LAT_;
  float a0 = 0.f, a1 = 0.f, a2 = 0.f, a3 = 0.f;
  for (int i = 0; i < LAT_; i += 64) {
    float w = wr[i + lane];
    a0 = __builtin_fmaf(w, slat[0 * LAT_ + i + lane], a0);
    a1 = __builtin_fmaf(w, slat[1 * LAT_ + i + lane], a1);
    a2 = __builtin_fmaf(w, slat[2 * LAT_ + i + lane], a2);
    a3 = __builtin_fmaf(w, slat[3 * LAT_ + i + lane], a3);
  }
  #pragma unroll
  for (int off = 32; off; off >>= 1) {
    a0 += __shfl_down(a0, off, 64);
    a1 += __shfl_down(a1, off, 64);
    a2 += __shfl_down(a2, off, 64);
    a3 += __shfl_down(a3, off, 64);
  }
  if (lane == 0) {
    float b = hb[j];
    hyp[0 * HYP_ + j] = a0 + b;
    hyp[1 * HYP_ + j] = a1 + b;
    hyp[2 * HYP_ + j] = a2 + b;
    hyp[3 * HYP_ + j] = a3 + b;
  }
}

// ---------------- dynamic weights -> STATIC split-bf16 frag layout (once) ---------
__global__ __launch_bounds__(256) void prep_dynw_kernel(float* wsm) {
  const int b = blockIdx.x >> 3, sl = blockIdx.x & 7;
  const int tid = threadIdx.x;
  const float* hyp = wsm + OFF_HYP + (size_t)b * HYP_;
  unsigned short* wfin = (unsigned short*)(wsm + OFF_WFIN) + (size_t)b * 24576;
  unsigned short* wfsh = (unsigned short*)(wsm + OFF_WFSH) + (size_t)b * 24576;
  unsigned short* wfmid = (unsigned short*)(wsm + OFF_WFMID) + (size_t)b * 8192;
  unsigned short* wfout = (unsigned short*)(wsm + OFF_WFOUT) + (size_t)b * 8192;

  if (sl < 6) {
    const int base = sl * 2048;
    for (int i = tid; i < 2048; i += 256) {
      int idx = base + i;
      int j = idx & 7, ch = (idx >> 3) & 63, g2 = (idx >> 9) & 3, ks = idx >> 11;
      int k = ks * 32 + g2 * 8 + j;
      int fbx = ((ks * 4 + g2) * 64 + ch) * 16;
      unsigned short h, l;
      split2(hyp[OFFI_WIN + ch * C3_ + k], h, l);
      wfin[fbx + j] = h; wfin[fbx + 8 + j] = l;
      split2(hyp[OFFI_WSH + ch * C3_ + k], h, l);
      wfsh[fbx + j] = h; wfsh[fbx + 8 + j] = l;
    }
  } else if (sl == 6) {
    for (int idx = tid; idx < 4096; idx += 256) {
      int j = idx & 7, ch = (idx >> 3) & 63, g2 = (idx >> 9) & 3, ks = idx >> 11;
      int k = ks * 32 + g2 * 8 + j;
      int fbx = ((ks * 4 + g2) * 64 + ch) * 16;
      unsigned short h, l;
      split2(hyp[OFFI_WMID + ch * 64 + k], h, l);
      wfmid[fbx + j] = h; wfmid[fbx + 8 + j] = l;
      split2(hyp[OFFI_WOUT + ch * 64 + k], h, l);
      wfout[fbx + j] = h; wfout[fbx + 8 + j] = l;
    }
  }
}

// ---------------- conv weights -> split-bf16 frag layout (+ img transpose) --------
__global__ __launch_bounds__(256) void prep_convw_kernel(
    const float* __restrict__ w1, const float* __restrict__ w2,
    const float* __restrict__ wi, unsigned short* __restrict__ wf1,
    unsigned short* __restrict__ wf2, float* __restrict__ wit) {
  const int idx = blockIdx.x * 256 + threadIdx.x;
  if (idx < 36864) {
    int j = idx & 7, ch = (idx >> 3) & 63, fg = idx >> 9;  // fg = ks*4+g
    int k = (fg >> 2) * 32 + (fg & 3) * 8 + j;
    int c = k & 63, t = k >> 6;
    int fb = (fg * 64 + ch) * 16;
    unsigned short h, l;
    split2(w1[(ch * 64 + c) * 9 + t], h, l);
    wf1[fb + j] = h; wf1[fb + 8 + j] = l;
    split2(w2[(ch * 64 + c) * 9 + t], h, l);
    wf2[fb + j] = h; wf2[fb + 8 + j] = l;
  }
  if (idx < 64 * 9 * 3) {
    int k = idx % 3, rest = idx / 3;
    int t = rest % 9, c = rest / 9;
    wit[idx] = wi[(k * 64 + c) * 9 + t];
  }
}

__device__ __forceinline__ void hline_z(const float* __restrict__ P, int rr, int col,
                                        float& hdv, float& hsv, float& cv) {
  if (rr < 0 || rr > 127) { hdv = 0.f; hsv = 0.f; cv = 0.f; return; }
  const float* rp = P + rr * HH_;
  float vm2 = (col >= 2) ? rp[col - 2] : 0.f;
  float vm1 = (col >= 1) ? rp[col - 1] : 0.f;
  float v0 = rp[col];
  float vp1 = (col <= 126) ? rp[col + 1] : 0.f;
  float vp2 = (col <= 125) ? rp[col + 2] : 0.f;
  hdv = -vm2 - R_ * vm1 + R_ * vp1 + vp2;
  hsv = R_ * vm1 + v0 + R_ * vp1;
  cv = v0;
}

// 8-wave block reduction (512-thread blocks)
__device__ __forceinline__ float blockReduceSum8(float v, float* scratch) {
  const int tid = threadIdx.x;
  #pragma unroll
  for (int off = 32; off; off >>= 1) v += __shfl_down(v, off, 64);
  if ((tid & 63) == 0) scratch[tid >> 6] = v;
  __syncthreads();
  float r = 0.f;
  #pragma unroll
  for (int w = 0; w < 8; ++w) r += scratch[w];
  __syncthreads();
  return r;
}

// ---------------- SinSobel -> packed split-bf16 gx/gy + raw IN partials -----------
// 512 threads: col = tid&127, strip = tid>>7 (8 rows each); 8 waves/block ->
// 32 waves/CU at 4 blocks/CU (was 16). Latency-bound kernel; more TLP.
__global__ __launch_bounds__(512) void sobel_stats_kernel(
    const float* __restrict__ outb, unsigned int* __restrict__ sob,
    float* __restrict__ sraw) {
  __shared__ float scr[8];
  const int bi = blockIdx.x;
  const int q = bi & 3, c = (bi >> 2) & 63, b = bi >> 8;
  const int tid = threadIdx.x;
  const int col = tid & 127;
  const int r0 = q * 32 + (tid >> 7) * 8;
  const float* P = outb + ((size_t)(b * F_ + c)) * NPIX_;
  unsigned int* ygx = sob + ((size_t)(b * 128 + 2 * c)) * NPIX_;
  unsigned int* ygy = ygx + NPIX_;

  float sI = 0.f, qI = 0.f, sX = 0.f, qX = 0.f, sY = 0.f, qY = 0.f;
  float hd_m1, hd_0, hd_p1, hs_m2, hs_m1, hs_0, hs_p1;
  float td, tc;
  hline_z(P, r0 - 2, col, td, hs_m2, tc);
  hline_z(P, r0 - 1, col, hd_m1, hs_m1, tc);
  hline_z(P, r0, col, hd_0, hs_0, tc);
  sI += tc; qI += tc * tc;
  hline_z(P, r0 + 1, col, hd_p1, hs_p1, tc);
  sI += tc; qI += tc * tc;

  for (int i = 0; i < 8; ++i) {
    const int r = r0 + i;
    const int nr = r + 2;
    float hd_new, hs_new, cnew;
    hline_z(P, nr, col, hd_new, hs_new, cnew);
    if (nr <= r0 + 7) { sI += cnew; qI += cnew * cnew; }
    float gxv = R_ * (hd_m1 + hd_p1) + hd_0;
    float gyv = -hs_m2 - R_ * hs_m1 + R_ * hs_p1 + hs_new;
    const int o = r * HH_ + col;
    unsigned short h, l;
    split2(gxv, h, l);
    ygx[o] = ((unsigned)h << 16) | l;
    split2(gyv, h, l);
    ygy[o] = ((unsigned)h << 16) | l;
    sX += gxv; qX += gxv * gxv;
    sY += gyv; qY += gyv * gyv;
    hd_m1 = hd_0; hd_0 = hd_p1; hd_p1 = hd_new;
    hs_m2 = hs_m1; hs_m1 = hs_0; hs_0 = hs_p1; hs_p1 = hs_new;
  }
  __syncthreads();
  float tI = blockReduceSum8(sI, scr);
  float tQI = blockReduceSum8(qI, scr);
  float tX = blockReduceSum8(sX, scr);
  float tQX = blockReduceSum8(qX, scr);
  float tY = blockReduceSum8(sY, scr);
  float tQY = blockReduceSum8(qY, scr);
  if (tid == 0) {
    float* r = sraw + (size_t)bi * 6;
    r[0] = tI; r[1] = tQI; r[2] = tX; r[3] = tQX; r[4] = tY; r[5] = tQY;
  }
}

// ---------------- MFMA dynamic MLP, split-bf16, wave-per-cg-slice (R10 form) ------
// res-trick: C-tile reconstructed from staged ynorm + bf16 residual -> no C re-read.
__global__ __launch_bounds__(256, 2) void mlp_mfma_kernel(
    float* __restrict__ outb, const unsigned int* __restrict__ sobu,
    const float* __restrict__ wsf, const float* __restrict__ leak) {
  __shared__ unsigned short yhi[64 * 200];
  __shared__ unsigned short ylo[64 * 200];
  __shared__ unsigned short hhi[64 * 72];
  __shared__ unsigned short hlo[64 * 72];
  __shared__ unsigned short resb[64 * 66];
  __shared__ float stl[C3_ * 2];
  __shared__ float ssig[64];
  const int bi = blockIdx.x;
  const int b = bi >> 8, t = bi & 255;
  const int px0 = t * 64;
  const int tid = threadIdx.x;

  // finalize InstanceNorm stats for this sample (64 threads x 3 channels each)
  if (tid < 64) {
    const int c = tid;
    const float* r = wsf + OFF_SRAW + ((size_t)(b * 64 + c) * 4) * 6;
    float sI = 0.f, qI = 0.f, sX = 0.f, qX = 0.f, sY = 0.f, qY = 0.f;
    #pragma unroll
    for (int q = 0; q < 4; ++q) {
      sI += r[q * 6 + 0]; qI += r[q * 6 + 1];
      sX += r[q * 6 + 2]; qX += r[q * 6 + 3];
      sY += r[q * 6 + 4]; qY += r[q * 6 + 5];
    }
    const float n = 1.f / 16384.f;
    float m, rs;
    m = sI * n; rs = rsqrtf(qI * n - m * m + EPS_);
    stl[c * 2] = m; stl[c * 2 + 1] = rs; ssig[c] = 1.f / rs;
    const int cx = 64 + 2 * c, cy = cx + 1;
    m = sX * n; stl[cx * 2] = m;          stl[cx * 2 + 1] = rsqrtf(qX * n - m * m + EPS_);
    m = sY * n; stl[cy * 2] = m;          stl[cy * 2 + 1] = rsqrtf(qY * n - m * m + EPS_);
  }
  __syncthreads();

  const float* ob = outb + (size_t)b * F_ * NPIX_;
  const unsigned int* sbp = sobu + (size_t)b * 128 * NPIX_;
  #pragma unroll
  for (int it = 0; it < 12; ++it) {
    int ci = it * 256 + tid;
    int k = ci >> 4, pq = ci & 15;
    int kk = k ^ ((pq >> 1) << 3);
    unsigned short* ph = &yhi[(pq * 4) * 200 + kk];
    unsigned short* pl = &ylo[(pq * 4) * 200 + kk];
    const float mu = stl[k * 2], inv = stl[k * 2 + 1];
    float vv[4];
    if (k < 64) {
      float4 f = *(const float4*)(ob + (size_t)k * NPIX_ + px0 + pq * 4);
      vv[0] = f.x; vv[1] = f.y; vv[2] = f.z; vv[3] = f.w;
      const float sg = ssig[k];
      #pragma unroll
      for (int e = 0; e < 4; ++e) {
        unsigned short h, l;
        split2((vv[e] - mu) * inv, h, l);
        ph[e * 200] = h; pl[e * 200] = l;
        float rec = __builtin_fmaf(b2f(h) + b2f(l), sg, mu);
        resb[k * 66 + pq * 4 + e] = f2b(vv[e] - rec);
      }
    } else {
      uint4 v = *(const uint4*)(sbp + (size_t)(k - 64) * NPIX_ + px0 + pq * 4);
      vv[0] = b2f((unsigned short)(v.x >> 16)) + b2f((unsigned short)(v.x & 0xffff));
      vv[1] = b2f((unsigned short)(v.y >> 16)) + b2f((unsigned short)(v.y & 0xffff));
      vv[2] = b2f((unsigned short)(v.z >> 16)) + b2f((unsigned short)(v.z & 0xffff));
      vv[3] = b2f((unsigned short)(v.w >> 16)) + b2f((unsigned short)(v.w & 0xffff));
      #pragma unroll
      for (int e = 0; e < 4; ++e) {
        unsigned short h, l;
        split2((vv[e] - mu) * inv, h, l);
        ph[e * 200] = h; pl[e * 200] = l;
      }
    }
  }
  __syncthreads();

  const int wave = tid >> 6, lane = tid & 63;
  const int lrow = lane & 15, g = lane >> 4;
  const int chm = wave * 16 + lrow;  // this wave's output-channel for this lane
  const float lf = fminf(fmaxf(leak[0], 0.001f), 1000.f);
  const float* hyp = wsf + OFF_HYP + (size_t)b * HYP_;
  const unsigned short* wfin = (const unsigned short*)(wsf + OFF_WFIN) + (size_t)b * 24576;
  const unsigned short* wfsh = (const unsigned short*)(wsf + OFF_WFSH) + (size_t)b * 24576;
  const unsigned short* wfmid = (const unsigned short*)(wsf + OFF_WFMID) + (size_t)b * 8192;
  const unsigned short* wfout = (const unsigned short*)(wsf + OFF_WFOUT) + (size_t)b * 8192;

  // ---- phase 1: h1 + shortcut (K = 192), B-frag shared across 4 px-frags ----
  f32x4 aH[4], aS[4];
  {
    float b1 = hyp[OFFI_BIN + chm], b2 = hyp[OFFI_BSH + chm];
    #pragma unroll
    for (int pf = 0; pf < 4; ++pf) {
      aH[pf] = (f32x4){b1, b1, b1, b1};
      aS[pf] = (f32x4){b2, b2, b2, b2};
    }
  }
  #pragma unroll
  for (int ks = 0; ks < 6; ++ks) {
    const size_t wo = (size_t)((ks * 4 + g) * 64 + chm) * 16;
    bf16x8 whiI = *(const bf16x8*)(wfin + wo);
    bf16x8 wloI = *(const bf16x8*)(wfin + wo + 8);
    bf16x8 whiS = *(const bf16x8*)(wfsh + wo);
    bf16x8 wloS = *(const bf16x8*)(wfsh + wo + 8);
    #pragma unroll
    for (int pf = 0; pf < 4; ++pf) {
      const int pxl = pf * 16 + lrow;
      const int kb = pxl * 200 + ((ks * 32 + g * 8) ^ ((pxl >> 3) << 3));
      bf16x8 ahi = *(const bf16x8*)&yhi[kb];
      bf16x8 alo = *(const bf16x8*)&ylo[kb];
      MM3(aH[pf], ahi, alo, whiI, wloI);
      MM3(aS[pf], ahi, alo, whiS, wloS);
    }
  }
  // lrelu(h1) -> htile: px = pf*16 + g*4 + j, ch = chm
  #pragma unroll
  for (int pf = 0; pf < 4; ++pf) {
    #pragma unroll
    for (int j = 0; j < 4; ++j) {
      float v = aH[pf][j];
      v = (v >= 0.f) ? v : NEG_ * v;
      unsigned short h, l;
      split2(v, h, l);
      const int o = (pf * 16 + g * 4 + j) * 72 + chm;
      hhi[o] = h; hlo[o] = l;
    }
  }
  __syncthreads();
  // ---- phase 2: h2 (K = 64) ----
  f32x4 aM[4];
  {
    float bm = hyp[OFFI_BMID + chm];
    #pragma unroll
    for (int pf = 0; pf < 4; ++pf) aM[pf] = (f32x4){bm, bm, bm, bm};
  }
  #pragma unroll
  for (int ks = 0; ks < 2; ++ks) {
    const size_t wo = (size_t)((ks * 4 + g) * 64 + chm) * 16;
    bf16x8 whi = *(const bf16x8*)(wfmid + wo);
    bf16x8 wlo = *(const bf16x8*)(wfmid + wo + 8);
    #pragma unroll
    for (int pf = 0; pf < 4; ++pf) {
      const int kb = (pf * 16 + lrow) * 72 + ks * 32 + g * 8;
      bf16x8 ahi = *(const bf16x8*)&hhi[kb];
      bf16x8 alo = *(const bf16x8*)&hlo[kb];
      MM3(aM[pf], ahi, alo, whi, wlo);
    }
  }
  __syncthreads();
  #pragma unroll
  for (int pf = 0; pf < 4; ++pf) {
    #pragma unroll
    for (int j = 0; j < 4; ++j) {
      float v = aM[pf][j];
      v = (v >= 0.f) ? v : NEG_ * v;
      unsigned short h, l;
      split2(v, h, l);
      const int o = (pf * 16 + g * 4 + j) * 72 + chm;
      hhi[o] = h; hlo[o] = l;
    }
  }
  __syncthreads();
  // ---- phase 3: h3 (K = 64) ----
  f32x4 aO[4];
  {
    float bo = hyp[OFFI_BOUT + chm];
    #pragma unroll
    for (int pf = 0; pf < 4; ++pf) aO[pf] = (f32x4){bo, bo, bo, bo};
  }
  #pragma unroll
  for (int ks = 0; ks < 2; ++ks) {
    const size_t wo = (size_t)((ks * 4 + g) * 64 + chm) * 16;
    bf16x8 whi = *(const bf16x8*)(wfout + wo);
    bf16x8 wlo = *(const bf16x8*)(wfout + wo + 8);
    #pragma unroll
    for (int pf = 0; pf < 4; ++pf) {
      const int kb = (pf * 16 + lrow) * 72 + ks * 32 + g * 8;
      bf16x8 ahi = *(const bf16x8*)&hhi[kb];
      bf16x8 alo = *(const bf16x8*)&hlo[kb];
      MM3(aO[pf], ahi, alo, whi, wlo);
    }
  }
  // ---- out = recon(ynorm, res) + lf*(h3 + shortcut): WRITE-ONLY to global ----
  const float mu_c = stl[chm * 2];
  const float sg_c = ssig[chm];
  #pragma unroll
  for (int pf = 0; pf < 4; ++pf) {
    float* op = outb + ((size_t)(b * F_ + chm)) * NPIX_ + px0 + pf * 16 + g * 4;
    f32x4 nv;
    #pragma unroll
    for (int j = 0; j < 4; ++j) {
      const int pxl = pf * 16 + g * 4 + j;
      const int kk2 = chm ^ ((pxl >> 3) << 3);
      float yv = b2f(yhi[pxl * 200 + kk2]) + b2f(ylo[pxl * 200 + kk2]);
      float vorig = __builtin_fmaf(yv, sg_c, mu_c) + b2f(resb[chm * 66 + pxl]);
      nv[j] = vorig + lf * (aO[pf][j] + aS[pf][j]);
    }
    *(f32x4*)op = nv;
  }
}

// ---------------- MFMA 3x3 conv (implicit GEMM, split-bf16, 2-row tiles) ----------
__global__ __launch_bounds__(256, 2) void conv_mfma_kernel(
    const float* __restrict__ in, const unsigned short* __restrict__ wf,
    const float* __restrict__ bias, float* __restrict__ dst, int mode) {
  __shared__ unsigned short ahi[4 * 72 * 64];
  __shared__ unsigned short alo[4 * 72 * 64];
  const int bi = blockIdx.x;
  const int b = bi >> 7, rest = bi & 127;
  const int row0 = (rest >> 1) * 2, colbase = (rest & 1) << 6;
  const int tid = threadIdx.x;
  const float* ip = in + (size_t)b * F_ * NPIX_;

  for (int idx = tid; idx < 4608; idx += 256) {
    const int chunk = idx % 18;
    const int rowp = (idx / 18) % 4;
    const int ch = idx / 72;
    const int r2 = row0 - 1 + rowp;
    const int gcol0 = colbase - 4 + chunk * 4;
    float4 v;
    if (r2 < 0 || r2 > 127) {
      v = make_float4(0.f, 0.f, 0.f, 0.f);
    } else if (gcol0 >= 0 && gcol0 <= 124) {
      v = *(const float4*)(ip + (size_t)ch * NPIX_ + r2 * HH_ + gcol0);
    } else {
      const float* rp = ip + (size_t)ch * NPIX_ + r2 * HH_;
      v.x = (gcol0 >= 0 && gcol0 < 128) ? rp[gcol0] : 0.f;
      v.y = (gcol0 + 1 >= 0 && gcol0 + 1 < 128) ? rp[gcol0 + 1] : 0.f;
      v.z = (gcol0 + 2 >= 0 && gcol0 + 2 < 128) ? rp[gcol0 + 2] : 0.f;
      v.w = (gcol0 + 3 >= 0 && gcol0 + 3 < 128) ? rp[gcol0 + 3] : 0.f;
    }
    const float vv[4] = {v.x, v.y, v.z, v.w};
    #pragma unroll
    for (int e = 0; e < 4; ++e) {
      const int i = chunk * 4 + e;
      const int sw = (((i >> 2) & 7) ^ ((i & 3) << 1) ^ rowp) << 3;
      const int a = (rowp * 72 + i) * 64 + (ch ^ sw);
      unsigned short h, l;
      split2(vv[e], h, l);
      ahi[a] = h; alo[a] = l;
    }
  }
  __syncthreads();

  const int wave = tid >> 6, lane = tid & 63;
  const int lrow = lane & 15, g = lane >> 4;
  const int pxl = wave * 16 + lrow;
  f32x4 acc0[4], acc1[4];
  #pragma unroll
  for (int cg = 0; cg < 4; ++cg) {
    float bz = bias[cg * 16 + lrow];
    acc0[cg] = (f32x4){bz, bz, bz, bz};
    acc1[cg] = (f32x4){bz, bz, bz, bz};
  }
  for (int ks = 0; ks < 18; ++ks) {
    const int kbase = ks * 32 + g * 8;
    const int t = kbase >> 6, c0 = kbase & 63;
    const int dy = t / 3 - 1, dx = t % 3 - 1;
    const int i = pxl + 4 + dx;
    const int rp0 = 1 + dy, rp1 = 2 + dy;
    const int sw0 = (((i >> 2) & 7) ^ ((i & 3) << 1) ^ rp0) << 3;
    const int sw1 = (((i >> 2) & 7) ^ ((i & 3) << 1) ^ rp1) << 3;
    const int a0 = (rp0 * 72 + i) * 64 + (c0 ^ sw0);
    const int a1 = (rp1 * 72 + i) * 64 + (c0 ^ sw1);
    bf16x8 ah0 = *(const bf16x8*)&ahi[a0];
    bf16x8 al0 = *(const bf16x8*)&alo[a0];
    bf16x8 ah1 = *(const bf16x8*)&ahi[a1];
    bf16x8 al1 = *(const bf16x8*)&alo[a1];
    #pragma unroll
    for (int cg = 0; cg < 4; ++cg) {
      const unsigned short* wp = wf + (size_t)((ks * 4 + g) * 64 + cg * 16 + lrow) * 16;
      bf16x8 whi = *(const bf16x8*)wp;
      bf16x8 wlo = *(const bf16x8*)(wp + 8);
      MM3(acc0[cg], ah0, al0, whi, wlo);
      MM3(acc1[cg], ah1, al1, whi, wlo);
    }
  }
  #pragma unroll
  for (int r = 0; r < 2; ++r) {
    #pragma unroll
    for (int cg = 0; cg < 4; ++cg) {
      const f32x4 av = r ? acc1[cg] : acc0[cg];
      float* op = dst + ((size_t)(b * F_ + cg * 16 + lrow)) * NPIX_ + (row0 + r) * HH_ +
                  colbase + wave * 16 + g * 4;
      if (mode == 1) {
        f32x4 rr;
        #pragma unroll
        for (int j = 0; j < 4; ++j) {
          float v = av[j];
          rr[j] = (v >= 0.f) ? v : NEG_ * v;
        }
        *(f32x4*)op = rr;
      } else {
        f32x4 cur = *(f32x4*)op;
        #pragma unroll
        for (int j = 0; j < 4; ++j) cur[j] += av[j];
        *(f32x4*)op = cur;
      }
    }
  }
}

// ---------------- final image conv (3 outputs, VALU) ------------------------------
__global__ __launch_bounds__(256, 4) void convimg_kernel(
    const float* __restrict__ outb, const float* __restrict__ wT,
    const float* __restrict__ bias, float* __restrict__ img) {
  __shared__ float part[2 * 128 * 3];
  const int bi = blockIdx.x;
  const int b = bi >> 7, pxb = bi & 127;
  const int tid = threadIdx.x;
  const int px = tid & 127;
  const int hf = __builtin_amdgcn_readfirstlane(tid >> 7);
  const int p = pxb * 128 + px;
  const int row = p >> 7, col = p & 127;
  float a0 = 0.f, a1 = 0.f, a2 = 0.f;
  const float* ip = outb + (size_t)b * F_ * NPIX_;
  for (int cc = 0; cc < 32; ++cc) {
    const int c = hf * 32 + cc;
    const float* pl = ip + (size_t)c * NPIX_;
    #pragma unroll
    for (int t = 0; t < 9; ++t) {
      const int dy = t / 3 - 1, dx = t % 3 - 1;
      const int r2 = row + dy, c2 = col + dx;
      float v = (r2 >= 0 && r2 < 128 && c2 >= 0 && c2 < 128) ? pl[r2 * HH_ + c2] : 0.f;
      const float* wp = wT + (c * 9 + t) * 3;
      a0 = __builtin_fmaf(v, wp[0], a0);
      a1 = __builtin_fmaf(v, wp[1], a1);
      a2 = __builtin_fmaf(v, wp[2], a2);
    }
  }
  part[(hf * 128 + px) * 3 + 0] = a0;
  part[(hf * 128 + px) * 3 + 1] = a1;
  part[(hf * 128 + px) * 3 + 2] = a2;
  __syncthreads();
  if (hf == 0) {
    float r0 = a0 + part[(128 + px) * 3 + 0] + bias[0];
    float r1 = a1 + part[(128 + px) * 3 + 1] + bias[1];
    float r2 = a2 + part[(128 + px) * 3 + 2] + bias[2];
    img[((size_t)b * 3 + 0) * NPIX_ + p] = fminf(fmaxf(r0, -1.f), 1.f);
    img[((size_t)b * 3 + 1) * NPIX_ + p] = fminf(fmaxf(r1, -1.f), 1.f);
    img[((size_t)b * 3 + 2) * NPIX_ + p] = fminf(fmaxf(r2, -1.f), 1.f);
  }
}

extern "C" void kernel_launch(void* const* d_in, const int* in_sizes, int n_in,
                              void* d_out, int out_size, void* d_ws, size_t ws_size,
                              hipStream_t stream) {
  const float* lat = (const float*)d_in[0];
  const float* ca_init = (const float*)d_in[1];
  const float* leak = (const float*)d_in[2];
  const float* hyper_w = (const float*)d_in[3];
  const float* hyper_b = (const float*)d_in[4];
  const float* res_w1 = (const float*)d_in[5];
  const float* res_b1 = (const float*)d_in[6];
  const float* res_w2 = (const float*)d_in[7];
  const float* res_b2 = (const float*)d_in[8];
  const float* img_w = (const float*)d_in[9];
  const float* img_b = (const float*)d_in[10];
  float* out = (float*)d_out;
  float* ws = (float*)d_ws;
  unsigned int* sobu = (unsigned int*)(ws + OFF_SOB);

  hyper_gemm_kernel<<<(HYP_ + 3) / 4, 256, 0, stream>>>(lat, hyper_w, hyper_b, ws + OFF_HYP);
  prep_dynw_kernel<<<32, 256, 0, stream>>>(ws);
  prep_convw_kernel<<<144, 256, 0, stream>>>(res_w1, res_w2, img_w,
                                             (unsigned short*)(ws + OFF_CW1),
                                             (unsigned short*)(ws + OFF_CW2),
                                             ws + OFF_CWIMG);
  hipMemcpyAsync(ws + OFF_OUT, ca_init, (size_t)B_ * F_ * NPIX_ * sizeof(float),
                 hipMemcpyDeviceToDevice, stream);

  for (int st = 0; st < 16; ++st) {
    sobel_stats_kernel<<<1024, 512, 0, stream>>>(ws + OFF_OUT, sobu, ws + OFF_SRAW);
    mlp_mfma_kernel<<<1024, 256, 0, stream>>>(ws + OFF_OUT, sobu, ws, leak);
  }

  conv_mfma_kernel<<<512, 256, 0, stream>>>(ws + OFF_OUT, (const unsigned short*)(ws + OFF_CW1),
                                            res_b1, (float*)(ws + OFF_TMP), 1);
  conv_mfma_kernel<<<512, 256, 0, stream>>>((const float*)(ws + OFF_TMP),
                                            (const unsigned short*)(ws + OFF_CW2),
                                            res_b2, ws + OFF_OUT, 2);
  convimg_kernel<<<512, 256, 0, stream>>>(ws + OFF_OUT, ws + OFF_CWIMG, img_b, out);
}

// Round 13
// 851.390 us; speedup vs baseline: 1.1106x; 1.0334x over previous
//
#include <hip/hip_runtime.h>
#include <cstddef>

#define R_ 0.70710678118654752f
#define NEG_ 0.2f
#define EPS_ 1e-5f

constexpr int F_ = 64, C3_ = 192, HH_ = 128, NPIX_ = 16384, B_ = 4, LAT_ = 512, HYP_ = 33024;
// intra-row offsets inside one sample's hypernet output
constexpr int OFFI_WIN = 0, OFFI_BIN = 12288, OFFI_WMID = 12352, OFFI_BMID = 16448,
              OFFI_WOUT = 16512, OFFI_BOUT = 20608, OFFI_WSH = 20672, OFFI_BSH = 32960;
// workspace layout (float offsets)
constexpr size_t OFF_HYP = 0;         // 132096
constexpr size_t OFF_SRAW = 134144;   // 6144
constexpr size_t OFF_WFIN = 140288;   // 4*24576 ushort = 49152 floats (hi/lo frag pairs)
constexpr size_t OFF_WFSH = 189440;   // 49152
constexpr size_t OFF_WFMID = 238592;  // 4*8192 ushort = 16384 floats
constexpr size_t OFF_WFOUT = 254976;  // 16384
constexpr size_t OFF_CW1 = 271360;    // 73728 ushort = 36864 floats (split-bf16 frag pairs)
constexpr size_t OFF_CW2 = 308224;    // 36864
constexpr size_t OFF_CWIMG = 345088;  // 1728
constexpr size_t OFF_OUT = 346816;    // 4194304
constexpr size_t OFF_SOB = 4541120;   // 4*128*16384 packed-uint = 8388608 "floats"
constexpr size_t OFF_TMP = OFF_SOB;   // epilogue h (fp32, 4194304) aliases sob
// total = 12,929,728 floats = 51.7 MB

typedef short bf16x8 __attribute__((ext_vector_type(8)));
typedef float f32x4 __attribute__((ext_vector_type(4)));

// fp32 -> bf16 (RNE)
static __device__ __forceinline__ unsigned short f2b(float v) {
  unsigned u = __builtin_bit_cast(unsigned, v);
  u += 0x7fffu + ((u >> 16) & 1u);
  return (unsigned short)(u >> 16);
}
static __device__ __forceinline__ float b2f(unsigned short h) {
  return __builtin_bit_cast(float, ((unsigned)h) << 16);
}
static __device__ __forceinline__ void split2(float v, unsigned short& hi, unsigned short& lo) {
  hi = f2b(v);
  lo = f2b(v - b2f(hi));
}

// triple-MFMA split-bf16 product: acc += Ahi*Whi + Ahi*Wlo + Alo*Whi
#define MM3(acc, ahi, alo, whi, wlo)                                        \
  acc = __builtin_amdgcn_mfma_f32_16x16x32_bf16(ahi, whi, acc, 0, 0, 0);    \
  acc = __builtin_amdgcn_mfma_f32_16x16x32_bf16(ahi, wlo, acc, 0, 0, 0);    \
  acc = __builtin_amdgcn_mfma_f32_16x16x32_bf16(alo, whi, acc, 0, 0, 0);

// ---------------- hypernetwork GEMM ----------------------------------------------
__global__ __launch_bounds__(256) void hyper_gemm_kernel(
    const float* __restrict__ lat, const float* __restrict__ hw,
    const float* __restrict__ hb, float* __restrict__ hyp) {
  __shared__ float slat[B_ * LAT_];
  const int tid = threadIdx.x;
  for (int i = tid; i < B_ * LAT_; i += 256) slat[i] = lat[i];
  __syncthreads();
  const int wave = tid >> 6, lane = tid & 63;
  const int j = blockIdx.x * 4 + wave;
  if (j >= HYP_) return;
  const float* wr = hw + (size_t)j * LAT_;
  float a0 = 0.f, a1 = 0.f, a2 = 0.f, a3 = 0.f;
  for (int i = 0; i < LAT_; i += 64) {
    float w = wr[i + lane];
    a0 = __builtin_fmaf(w, slat[0 * LAT_ + i + lane], a0);
    a1 = __builtin_fmaf(w, slat[1 * LAT_ + i + lane], a1);
    a2 = __builtin_fmaf(w, slat[2 * LAT_ + i + lane], a2);
    a3 = __builtin_fmaf(w, slat[3 * LAT_ + i + lane], a3);
  }
  #pragma unroll
  for (int off = 32; off; off >>= 1) {
    a0 += __shfl_down(a0, off, 64);
    a1 += __shfl_down(a1, off, 64);
    a2 += __shfl_down(a2, off, 64);
    a3 += __shfl_down(a3, off, 64);
  }
  if (lane == 0) {
    float b = hb[j];
    hyp[0 * HYP_ + j] = a0 + b;
    hyp[1 * HYP_ + j] = a1 + b;
    hyp[2 * HYP_ + j] = a2 + b;
    hyp[3 * HYP_ + j] = a3 + b;
  }
}

// ---------------- dynamic weights -> STATIC split-bf16 frag layout (once) ---------
__global__ __launch_bounds__(256) void prep_dynw_kernel(float* wsm) {
  const int b = blockIdx.x >> 3, sl = blockIdx.x & 7;
  const int tid = threadIdx.x;
  const float* hyp = wsm + OFF_HYP + (size_t)b * HYP_;
  unsigned short* wfin = (unsigned short*)(wsm + OFF_WFIN) + (size_t)b * 24576;
  unsigned short* wfsh = (unsigned short*)(wsm + OFF_WFSH) + (size_t)b * 24576;
  unsigned short* wfmid = (unsigned short*)(wsm + OFF_WFMID) + (size_t)b * 8192;
  unsigned short* wfout = (unsigned short*)(wsm + OFF_WFOUT) + (size_t)b * 8192;

  if (sl < 6) {
    const int base = sl * 2048;
    for (int i = tid; i < 2048; i += 256) {
      int idx = base + i;
      int j = idx & 7, ch = (idx >> 3) & 63, g2 = (idx >> 9) & 3, ks = idx >> 11;
      int k = ks * 32 + g2 * 8 + j;
      int fbx = ((ks * 4 + g2) * 64 + ch) * 16;
      unsigned short h, l;
      split2(hyp[OFFI_WIN + ch * C3_ + k], h, l);
      wfin[fbx + j] = h; wfin[fbx + 8 + j] = l;
      split2(hyp[OFFI_WSH + ch * C3_ + k], h, l);
      wfsh[fbx + j] = h; wfsh[fbx + 8 + j] = l;
    }
  } else if (sl == 6) {
    for (int idx = tid; idx < 4096; idx += 256) {
      int j = idx & 7, ch = (idx >> 3) & 63, g2 = (idx >> 9) & 3, ks = idx >> 11;
      int k = ks * 32 + g2 * 8 + j;
      int fbx = ((ks * 4 + g2) * 64 + ch) * 16;
      unsigned short h, l;
      split2(hyp[OFFI_WMID + ch * 64 + k], h, l);
      wfmid[fbx + j] = h; wfmid[fbx + 8 + j] = l;
      split2(hyp[OFFI_WOUT + ch * 64 + k], h, l);
      wfout[fbx + j] = h; wfout[fbx + 8 + j] = l;
    }
  }
}

// ---------------- conv weights -> split-bf16 frag layout (+ img transpose) --------
__global__ __launch_bounds__(256) void prep_convw_kernel(
    const float* __restrict__ w1, const float* __restrict__ w2,
    const float* __restrict__ wi, unsigned short* __restrict__ wf1,
    unsigned short* __restrict__ wf2, float* __restrict__ wit) {
  const int idx = blockIdx.x * 256 + threadIdx.x;
  if (idx < 36864) {
    int j = idx & 7, ch = (idx >> 3) & 63, fg = idx >> 9;  // fg = ks*4+g
    int k = (fg >> 2) * 32 + (fg & 3) * 8 + j;
    int c = k & 63, t = k >> 6;
    int fb = (fg * 64 + ch) * 16;
    unsigned short h, l;
    split2(w1[(ch * 64 + c) * 9 + t], h, l);
    wf1[fb + j] = h; wf1[fb + 8 + j] = l;
    split2(w2[(ch * 64 + c) * 9 + t], h, l);
    wf2[fb + j] = h; wf2[fb + 8 + j] = l;
  }
  if (idx < 64 * 9 * 3) {
    int k = idx % 3, rest = idx / 3;
    int t = rest % 9, c = rest / 9;
    wit[idx] = wi[(k * 64 + c) * 9 + t];
  }
}

__device__ __forceinline__ void hline_z(const float* __restrict__ P, int rr, int col,
                                        float& hdv, float& hsv, float& cv) {
  if (rr < 0 || rr > 127) { hdv = 0.f; hsv = 0.f; cv = 0.f; return; }
  const float* rp = P + rr * HH_;
  float vm2 = (col >= 2) ? rp[col - 2] : 0.f;
  float vm1 = (col >= 1) ? rp[col - 1] : 0.f;
  float v0 = rp[col];
  float vp1 = (col <= 126) ? rp[col + 1] : 0.f;
  float vp2 = (col <= 125) ? rp[col + 2] : 0.f;
  hdv = -vm2 - R_ * vm1 + R_ * vp1 + vp2;
  hsv = R_ * vm1 + v0 + R_ * vp1;
  cv = v0;
}

// 8-wave block reduction (512-thread blocks)
__device__ __forceinline__ float blockReduceSum8(float v, float* scratch) {
  const int tid = threadIdx.x;
  #pragma unroll
  for (int off = 32; off; off >>= 1) v += __shfl_down(v, off, 64);
  if ((tid & 63) == 0) scratch[tid >> 6] = v;
  __syncthreads();
  float r = 0.f;
  #pragma unroll
  for (int w = 0; w < 8; ++w) r += scratch[w];
  __syncthreads();
  return r;
}

// ---------------- SinSobel -> packed split-bf16 gx/gy + raw IN partials -----------
__global__ __launch_bounds__(512) void sobel_stats_kernel(
    const float* __restrict__ outb, unsigned int* __restrict__ sob,
    float* __restrict__ sraw) {
  __shared__ float scr[8];
  const int bi = blockIdx.x;
  const int q = bi & 3, c = (bi >> 2) & 63, b = bi >> 8;
  const int tid = threadIdx.x;
  const int col = tid & 127;
  const int r0 = q * 32 + (tid >> 7) * 8;
  const float* P = outb + ((size_t)(b * F_ + c)) * NPIX_;
  unsigned int* ygx = sob + ((size_t)(b * 128 + 2 * c)) * NPIX_;
  unsigned int* ygy = ygx + NPIX_;

  float sI = 0.f, qI = 0.f, sX = 0.f, qX = 0.f, sY = 0.f, qY = 0.f;
  float hd_m1, hd_0, hd_p1, hs_m2, hs_m1, hs_0, hs_p1;
  float td, tc;
  hline_z(P, r0 - 2, col, td, hs_m2, tc);
  hline_z(P, r0 - 1, col, hd_m1, hs_m1, tc);
  hline_z(P, r0, col, hd_0, hs_0, tc);
  sI += tc; qI += tc * tc;
  hline_z(P, r0 + 1, col, hd_p1, hs_p1, tc);
  sI += tc; qI += tc * tc;

  for (int i = 0; i < 8; ++i) {
    const int r = r0 + i;
    const int nr = r + 2;
    float hd_new, hs_new, cnew;
    hline_z(P, nr, col, hd_new, hs_new, cnew);
    if (nr <= r0 + 7) { sI += cnew; qI += cnew * cnew; }
    float gxv = R_ * (hd_m1 + hd_p1) + hd_0;
    float gyv = -hs_m2 - R_ * hs_m1 + R_ * hs_p1 + hs_new;
    const int o = r * HH_ + col;
    unsigned short h, l;
    split2(gxv, h, l);
    ygx[o] = ((unsigned)h << 16) | l;
    split2(gyv, h, l);
    ygy[o] = ((unsigned)h << 16) | l;
    sX += gxv; qX += gxv * gxv;
    sY += gyv; qY += gyv * gyv;
    hd_m1 = hd_0; hd_0 = hd_p1; hd_p1 = hd_new;
    hs_m2 = hs_m1; hs_m1 = hs_0; hs_0 = hs_p1; hs_p1 = hs_new;
  }
  __syncthreads();
  float tI = blockReduceSum8(sI, scr);
  float tQI = blockReduceSum8(qI, scr);
  float tX = blockReduceSum8(sX, scr);
  float tQX = blockReduceSum8(qX, scr);
  float tY = blockReduceSum8(sY, scr);
  float tQY = blockReduceSum8(qY, scr);
  if (tid == 0) {
    float* r = sraw + (size_t)bi * 6;
    r[0] = tI; r[1] = tQI; r[2] = tX; r[3] = tQX; r[4] = tY; r[5] = tQY;
  }
}

// ---------------- MFMA dynamic MLP, split-bf16, wave-per-cg-slice -----------------
// 3 blocks/CU: K-chunked staging (2 x 96 k, stride 136 = same bank class as the
// proven 200) + no res-trick (C re-read, L3-resident) + h stride 66.
// LDS = 2*64*136*2 + 2*64*66*2 + 1536 = 53,248 B -> 3 blocks/CU.
__global__ __launch_bounds__(256, 3) void mlp_mfma_kernel(
    float* __restrict__ outb, const unsigned int* __restrict__ sobu,
    const float* __restrict__ wsf, const float* __restrict__ leak) {
  __shared__ unsigned short yhi[64 * 136];
  __shared__ unsigned short ylo[64 * 136];
  __shared__ unsigned short hhi[64 * 66];
  __shared__ unsigned short hlo[64 * 66];
  __shared__ float stl[C3_ * 2];
  const int bi = blockIdx.x;
  const int b = bi >> 8, t = bi & 255;
  const int px0 = t * 64;
  const int tid = threadIdx.x;

  // finalize InstanceNorm stats for this sample (64 threads x 3 channels each)
  if (tid < 64) {
    const int c = tid;
    const float* r = wsf + OFF_SRAW + ((size_t)(b * 64 + c) * 4) * 6;
    float sI = 0.f, qI = 0.f, sX = 0.f, qX = 0.f, sY = 0.f, qY = 0.f;
    #pragma unroll
    for (int q = 0; q < 4; ++q) {
      sI += r[q * 6 + 0]; qI += r[q * 6 + 1];
      sX += r[q * 6 + 2]; qX += r[q * 6 + 3];
      sY += r[q * 6 + 4]; qY += r[q * 6 + 5];
    }
    const float n = 1.f / 16384.f;
    float m;
    m = sI * n; stl[c * 2] = m;           stl[c * 2 + 1] = rsqrtf(qI * n - m * m + EPS_);
    const int cx = 64 + 2 * c, cy = cx + 1;
    m = sX * n; stl[cx * 2] = m;          stl[cx * 2 + 1] = rsqrtf(qX * n - m * m + EPS_);
    m = sY * n; stl[cy * 2] = m;          stl[cy * 2 + 1] = rsqrtf(qY * n - m * m + EPS_);
  }
  __syncthreads();

  const float* ob = outb + (size_t)b * F_ * NPIX_;
  const unsigned int* sbp = sobu + (size_t)b * 128 * NPIX_;
  const int wave = tid >> 6, lane = tid & 63;
  const int lrow = lane & 15, g = lane >> 4;
  const int chm = wave * 16 + lrow;  // this wave's output-channel for this lane
  const float lf = fminf(fmaxf(leak[0], 0.001f), 1000.f);
  const float* hyp = wsf + OFF_HYP + (size_t)b * HYP_;
  const unsigned short* wfin = (const unsigned short*)(wsf + OFF_WFIN) + (size_t)b * 24576;
  const unsigned short* wfsh = (const unsigned short*)(wsf + OFF_WFSH) + (size_t)b * 24576;
  const unsigned short* wfmid = (const unsigned short*)(wsf + OFF_WFMID) + (size_t)b * 8192;
  const unsigned short* wfout = (const unsigned short*)(wsf + OFF_WFOUT) + (size_t)b * 8192;

  // ---- phase 1: h1 + shortcut (K = 192, two 96-k chunks) ----
  f32x4 aH[4], aS[4];
  {
    float b1 = hyp[OFFI_BIN + chm], b2 = hyp[OFFI_BSH + chm];
    #pragma unroll
    for (int pf = 0; pf < 4; ++pf) {
      aH[pf] = (f32x4){b1, b1, b1, b1};
      aS[pf] = (f32x4){b2, b2, b2, b2};
    }
  }
  #pragma unroll
  for (int c0 = 0; c0 < 2; ++c0) {
    if (c0) __syncthreads();  // chunk-1 MFMA must finish before restaging
    #pragma unroll
    for (int it = 0; it < 6; ++it) {
      const int ci = it * 256 + tid;
      const int kl = ci >> 4, pq = ci & 15;
      const int k = c0 * 96 + kl;
      const int kk = kl ^ ((pq >> 1) << 3);
      unsigned short* ph = &yhi[(pq * 4) * 136 + kk];
      unsigned short* pl = &ylo[(pq * 4) * 136 + kk];
      const float mu = stl[k * 2], inv = stl[k * 2 + 1];
      if (k < 64) {
        float4 f = *(const float4*)(ob + (size_t)k * NPIX_ + px0 + pq * 4);
        const float vv[4] = {f.x, f.y, f.z, f.w};
        #pragma unroll
        for (int e = 0; e < 4; ++e) {
          unsigned short h, l;
          split2((vv[e] - mu) * inv, h, l);
          ph[e * 136] = h; pl[e * 136] = l;
        }
      } else {
        uint4 v = *(const uint4*)(sbp + (size_t)(k - 64) * NPIX_ + px0 + pq * 4);
        const unsigned uu[4] = {v.x, v.y, v.z, v.w};
        #pragma unroll
        for (int e = 0; e < 4; ++e) {
          float val = b2f((unsigned short)(uu[e] >> 16)) + b2f((unsigned short)(uu[e] & 0xffff));
          unsigned short h, l;
          split2((val - mu) * inv, h, l);
          ph[e * 136] = h; pl[e * 136] = l;
        }
      }
    }
    __syncthreads();
    #pragma unroll
    for (int ks3 = 0; ks3 < 3; ++ks3) {
      const int ks = c0 * 3 + ks3;
      const size_t wo = (size_t)((ks * 4 + g) * 64 + chm) * 16;
      bf16x8 whiI = *(const bf16x8*)(wfin + wo);
      bf16x8 wloI = *(const bf16x8*)(wfin + wo + 8);
      bf16x8 whiS = *(const bf16x8*)(wfsh + wo);
      bf16x8 wloS = *(const bf16x8*)(wfsh + wo + 8);
      #pragma unroll
      for (int pf = 0; pf < 4; ++pf) {
        const int pxl = pf * 16 + lrow;
        const int kb = pxl * 136 + ((ks3 * 32 + g * 8) ^ ((pxl >> 3) << 3));
        bf16x8 ahi = *(const bf16x8*)&yhi[kb];
        bf16x8 alo = *(const bf16x8*)&ylo[kb];
        MM3(aH[pf], ahi, alo, whiI, wloI);
        MM3(aS[pf], ahi, alo, whiS, wloS);
      }
    }
  }
  // lrelu(h1) -> htile: px = pf*16 + g*4 + j, ch = chm
  #pragma unroll
  for (int pf = 0; pf < 4; ++pf) {
    #pragma unroll
    for (int j = 0; j < 4; ++j) {
      float v = aH[pf][j];
      v = (v >= 0.f) ? v : NEG_ * v;
      unsigned short h, l;
      split2(v, h, l);
      const int o = (pf * 16 + g * 4 + j) * 66 + chm;
      hhi[o] = h; hlo[o] = l;
    }
  }
  __syncthreads();
  // ---- phase 2: h2 (K = 64) ----
  f32x4 aM[4];
  {
    float bm = hyp[OFFI_BMID + chm];
    #pragma unroll
    for (int pf = 0; pf < 4; ++pf) aM[pf] = (f32x4){bm, bm, bm, bm};
  }
  #pragma unroll
  for (int ks = 0; ks < 2; ++ks) {
    const size_t wo = (size_t)((ks * 4 + g) * 64 + chm) * 16;
    bf16x8 whi = *(const bf16x8*)(wfmid + wo);
    bf16x8 wlo = *(const bf16x8*)(wfmid + wo + 8);
    #pragma unroll
    for (int pf = 0; pf < 4; ++pf) {
      const int kb = (pf * 16 + lrow) * 66 + ks * 32 + g * 8;
      bf16x8 ahi = *(const bf16x8*)&hhi[kb];
      bf16x8 alo = *(const bf16x8*)&hlo[kb];
      MM3(aM[pf], ahi, alo, whi, wlo);
    }
  }
  __syncthreads();
  #pragma unroll
  for (int pf = 0; pf < 4; ++pf) {
    #pragma unroll
    for (int j = 0; j < 4; ++j) {
      float v = aM[pf][j];
      v = (v >= 0.f) ? v : NEG_ * v;
      unsigned short h, l;
      split2(v, h, l);
      const int o = (pf * 16 + g * 4 + j) * 66 + chm;
      hhi[o] = h; hlo[o] = l;
    }
  }
  __syncthreads();
  // ---- phase 3: h3 (K = 64) ----
  f32x4 aO[4];
  {
    float bo = hyp[OFFI_BOUT + chm];
    #pragma unroll
    for (int pf = 0; pf < 4; ++pf) aO[pf] = (f32x4){bo, bo, bo, bo};
  }
  #pragma unroll
  for (int ks = 0; ks < 2; ++ks) {
    const size_t wo = (size_t)((ks * 4 + g) * 64 + chm) * 16;
    bf16x8 whi = *(const bf16x8*)(wfout + wo);
    bf16x8 wlo = *(const bf16x8*)(wfout + wo + 8);
    #pragma unroll
    for (int pf = 0; pf < 4; ++pf) {
      const int kb = (pf * 16 + lrow) * 66 + ks * 32 + g * 8;
      bf16x8 ahi = *(const bf16x8*)&hhi[kb];
      bf16x8 alo = *(const bf16x8*)&hlo[kb];
      MM3(aO[pf], ahi, alo, whi, wlo);
    }
  }
  // ---- out += lf * (h3 + shortcut): C re-read (L3-resident, R8-proven) ----
  #pragma unroll
  for (int pf = 0; pf < 4; ++pf) {
    float* op = outb + ((size_t)(b * F_ + chm)) * NPIX_ + px0 + pf * 16 + g * 4;
    f32x4 cur = *(f32x4*)op;
    #pragma unroll
    for (int j = 0; j < 4; ++j) cur[j] += lf * (aO[pf][j] + aS[pf][j]);
    *(f32x4*)op = cur;
  }
}

// ---------------- MFMA 3x3 conv (implicit GEMM, split-bf16, 2-row tiles) ----------
__global__ __launch_bounds__(256, 2) void conv_mfma_kernel(
    const float* __restrict__ in, const unsigned short* __restrict__ wf,
    const float* __restrict__ bias, float* __restrict__ dst, int mode) {
  __shared__ unsigned short ahi[4 * 72 * 64];
  __shared__ unsigned short alo[4 * 72 * 64];
  const int bi = blockIdx.x;
  const int b = bi >> 7, rest = bi & 127;
  const int row0 = (rest >> 1) * 2, colbase = (rest & 1) << 6;
  const int tid = threadIdx.x;
  const float* ip = in + (size_t)b * F_ * NPIX_;

  for (int idx = tid; idx < 4608; idx += 256) {
    const int chunk = idx % 18;
    const int rowp = (idx / 18) % 4;
    const int ch = idx / 72;
    const int r2 = row0 - 1 + rowp;
    const int gcol0 = colbase - 4 + chunk * 4;
    float4 v;
    if (r2 < 0 || r2 > 127) {
      v = make_float4(0.f, 0.f, 0.f, 0.f);
    } else if (gcol0 >= 0 && gcol0 <= 124) {
      v = *(const float4*)(ip + (size_t)ch * NPIX_ + r2 * HH_ + gcol0);
    } else {
      const float* rp = ip + (size_t)ch * NPIX_ + r2 * HH_;
      v.x = (gcol0 >= 0 && gcol0 < 128) ? rp[gcol0] : 0.f;
      v.y = (gcol0 + 1 >= 0 && gcol0 + 1 < 128) ? rp[gcol0 + 1] : 0.f;
      v.z = (gcol0 + 2 >= 0 && gcol0 + 2 < 128) ? rp[gcol0 + 2] : 0.f;
      v.w = (gcol0 + 3 >= 0 && gcol0 + 3 < 128) ? rp[gcol0 + 3] : 0.f;
    }
    const float vv[4] = {v.x, v.y, v.z, v.w};
    #pragma unroll
    for (int e = 0; e < 4; ++e) {
      const int i = chunk * 4 + e;
      const int sw = (((i >> 2) & 7) ^ ((i & 3) << 1) ^ rowp) << 3;
      const int a = (rowp * 72 + i) * 64 + (ch ^ sw);
      unsigned short h, l;
      split2(vv[e], h, l);
      ahi[a] = h; alo[a] = l;
    }
  }
  __syncthreads();

  const int wave = tid >> 6, lane = tid & 63;
  const int lrow = lane & 15, g = lane >> 4;
  const int pxl = wave * 16 + lrow;
  f32x4 acc0[4], acc1[4];
  #pragma unroll
  for (int cg = 0; cg < 4; ++cg) {
    float bz = bias[cg * 16 + lrow];
    acc0[cg] = (f32x4){bz, bz, bz, bz};
    acc1[cg] = (f32x4){bz, bz, bz, bz};
  }
  for (int ks = 0; ks < 18; ++ks) {
    const int kbase = ks * 32 + g * 8;
    const int t = kbase >> 6, c0 = kbase & 63;
    const int dy = t / 3 - 1, dx = t % 3 - 1;
    const int i = pxl + 4 + dx;
    const int rp0 = 1 + dy, rp1 = 2 + dy;
    const int sw0 = (((i >> 2) & 7) ^ ((i & 3) << 1) ^ rp0) << 3;
    const int sw1 = (((i >> 2) & 7) ^ ((i & 3) << 1) ^ rp1) << 3;
    const int a0 = (rp0 * 72 + i) * 64 + (c0 ^ sw0);
    const int a1 = (rp1 * 72 + i) * 64 + (c0 ^ sw1);
    bf16x8 ah0 = *(const bf16x8*)&ahi[a0];
    bf16x8 al0 = *(const bf16x8*)&alo[a0];
    bf16x8 ah1 = *(const bf16x8*)&ahi[a1];
    bf16x8 al1 = *(const bf16x8*)&alo[a1];
    #pragma unroll
    for (int cg = 0; cg < 4; ++cg) {
      const unsigned short* wp = wf + (size_t)((ks * 4 + g) * 64 + cg * 16 + lrow) * 16;
      bf16x8 whi = *(const bf16x8*)wp;
      bf16x8 wlo = *(const bf16x8*)(wp + 8);
      MM3(acc0[cg], ah0, al0, whi, wlo);
      MM3(acc1[cg], ah1, al1, whi, wlo);
    }
  }
  #pragma unroll
  for (int r = 0; r < 2; ++r) {
    #pragma unroll
    for (int cg = 0; cg < 4; ++cg) {
      const f32x4 av = r ? acc1[cg] : acc0[cg];
      float* op = dst + ((size_t)(b * F_ + cg * 16 + lrow)) * NPIX_ + (row0 + r) * HH_ +
                  colbase + wave * 16 + g * 4;
      if (mode == 1) {
        f32x4 rr;
        #pragma unroll
        for (int j = 0; j < 4; ++j) {
          float v = av[j];
          rr[j] = (v >= 0.f) ? v : NEG_ * v;
        }
        *(f32x4*)op = rr;
      } else {
        f32x4 cur = *(f32x4*)op;
        #pragma unroll
        for (int j = 0; j < 4; ++j) cur[j] += av[j];
        *(f32x4*)op = cur;
      }
    }
  }
}

// ---------------- final image conv (3 outputs, VALU, 4-way ch split) --------------
__global__ __launch_bounds__(256, 4) void convimg_kernel(
    const float* __restrict__ outb, const float* __restrict__ wT,
    const float* __restrict__ bias, float* __restrict__ img) {
  __shared__ float part[4 * 64 * 3];
  const int bi = blockIdx.x;
  const int b = bi >> 8, tile = bi & 255;
  const int tid = threadIdx.x;
  const int px = tid & 63;
  const int hf = __builtin_amdgcn_readfirstlane(tid >> 6);  // wave index, 0..3
  const int p = tile * 64 + px;
  const int row = p >> 7, col = p & 127;
  float a0 = 0.f, a1 = 0.f, a2 = 0.f;
  const float* ip = outb + (size_t)b * F_ * NPIX_;
  for (int cc = 0; cc < 16; ++cc) {
    const int c = hf * 16 + cc;
    const float* pl = ip + (size_t)c * NPIX_;
    #pragma unroll
    for (int t = 0; t < 9; ++t) {
      const int dy = t / 3 - 1, dx = t % 3 - 1;
      const int r2 = row + dy, c2 = col + dx;
      float v = (r2 >= 0 && r2 < 128 && c2 >= 0 && c2 < 128) ? pl[r2 * HH_ + c2] : 0.f;
      const float* wp = wT + (c * 9 + t) * 3;
      a0 = __builtin_fmaf(v, wp[0], a0);
      a1 = __builtin_fmaf(v, wp[1], a1);
      a2 = __builtin_fmaf(v, wp[2], a2);
    }
  }
  part[(hf * 64 + px) * 3 + 0] = a0;
  part[(hf * 64 + px) * 3 + 1] = a1;
  part[(hf * 64 + px) * 3 + 2] = a2;
  __syncthreads();
  if (hf == 0) {
    float r0 = a0 + bias[0], r1 = a1 + bias[1], r2 = a2 + bias[2];
    #pragma unroll
    for (int w = 1; w < 4; ++w) {
      r0 += part[(w * 64 + px) * 3 + 0];
      r1 += part[(w * 64 + px) * 3 + 1];
      r2 += part[(w * 64 + px) * 3 + 2];
    }
    img[((size_t)b * 3 + 0) * NPIX_ + p] = fminf(fmaxf(r0, -1.f), 1.f);
    img[((size_t)b * 3 + 1) * NPIX_ + p] = fminf(fmaxf(r1, -1.f), 1.f);
    img[((size_t)b * 3 + 2) * NPIX_ + p] = fminf(fmaxf(r2, -1.f), 1.f);
  }
}

extern "C" void kernel_launch(void* const* d_in, const int* in_sizes, int n_in,
                              void* d_out, int out_size, void* d_ws, size_t ws_size,
                              hipStream_t stream) {
  const float* lat = (const float*)d_in[0];
  const float* ca_init = (const float*)d_in[1];
  const float* leak = (const float*)d_in[2];
  const float* hyper_w = (const float*)d_in[3];
  const float* hyper_b = (const float*)d_in[4];
  const float* res_w1 = (const float*)d_in[5];
  const float* res_b1 = (const float*)d_in[6];
  const float* res_w2 = (const float*)d_in[7];
  const float* res_b2 = (const float*)d_in[8];
  const float* img_w = (const float*)d_in[9];
  const float* img_b = (const float*)d_in[10];
  float* out = (float*)d_out;
  float* ws = (float*)d_ws;
  unsigned int* sobu = (unsigned int*)(ws + OFF_SOB);

  hyper_gemm_kernel<<<(HYP_ + 3) / 4, 256, 0, stream>>>(lat, hyper_w, hyper_b, ws + OFF_HYP);
  prep_dynw_kernel<<<32, 256, 0, stream>>>(ws);
  prep_convw_kernel<<<144, 256, 0, stream>>>(res_w1, res_w2, img_w,
                                             (unsigned short*)(ws + OFF_CW1),
                                             (unsigned short*)(ws + OFF_CW2),
                                             ws + OFF_CWIMG);
  hipMemcpyAsync(ws + OFF_OUT, ca_init, (size_t)B_ * F_ * NPIX_ * sizeof(float),
                 hipMemcpyDeviceToDevice, stream);

  for (int st = 0; st < 16; ++st) {
    sobel_stats_kernel<<<1024, 512, 0, stream>>>(ws + OFF_OUT, sobu, ws + OFF_SRAW);
    mlp_mfma_kernel<<<1024, 256, 0, stream>>>(ws + OFF_OUT, sobu, ws, leak);
  }

  conv_mfma_kernel<<<512, 256, 0, stream>>>(ws + OFF_OUT, (const unsigned short*)(ws + OFF_CW1),
                                            res_b1, (float*)(ws + OFF_TMP), 1);
  conv_mfma_kernel<<<512, 256, 0, stream>>>((const float*)(ws + OFF_TMP),
                                            (const unsigned short*)(ws + OFF_CW2),
                                            res_b2, ws + OFF_OUT, 2);
  convimg_kernel<<<1024, 256, 0, stream>>>(ws + OFF_OUT, ws + OFF_CWIMG, img_b, out);
}